// Round 9
// baseline (137.815 us; speedup 1.0000x reference)
//
#include <hip/hip_runtime.h>
#include <hip/hip_bf16.h>

#define S_LEN   2048
#define D_MODEL 1024
#define N_HEADS 16
#define N_GROUPS 4
#define D_K     64
#define KV_DIM  (N_GROUPS * D_K)   // 256

typedef __hip_bfloat16 bf16;
typedef unsigned short u16;
typedef __attribute__((ext_vector_type(8))) short bfrag;   // 8 bf16 = 4 VGPR
typedef __attribute__((ext_vector_type(4))) float ffrag;   // 4 fp32 acc
typedef __attribute__((ext_vector_type(4))) unsigned int u32x4;

__device__ __forceinline__ float b2f(u16 u) {
    return __uint_as_float(((unsigned)u) << 16);
}
__device__ __forceinline__ u16 f2bu(float f) {
    bf16 h = __float2bfloat16(f);
    return __builtin_bit_cast(u16, h);
}
__device__ __forceinline__ unsigned cvt_pk_bf16(float lo, float hi) {
    unsigned r;
    asm("v_cvt_pk_bf16_f32 %0, %1, %2" : "=v"(r) : "v"(lo), "v"(hi));
    return r;
}
__device__ __forceinline__ float max3f(float a, float b, float c) {
    float d;
    asm("v_max3_f32 %0, %1, %2, %3" : "=v"(d) : "v"(a), "v"(b), "v"(c));
    return d;
}
__device__ __forceinline__ float ex2(float x) {
#if __has_builtin(__builtin_amdgcn_exp2f)
    return __builtin_amdgcn_exp2f(x);
#else
    return __expf(x * 0.69314718f);
#endif
}

typedef __attribute__((address_space(3))) u16 lds_u16;
typedef __attribute__((address_space(1))) const u16 glb_u16;
__device__ __forceinline__ void gld_lds16(const u16* g, u16* l) {
    __builtin_amdgcn_global_load_lds((glb_u16*)g, (lds_u16*)l, 16, 0, 0);
}

// ---- longest-first chunk schedule for CS=3, QBLK=128 (40 chunks) ----
// Full (nt=8) chunks: (i,c) with i >= 4c+3 -> positions 0..27 (c-major).
// Partial chunks nt=2d (d=i-4c+1 in {1,2,3}) at 28+(3-d)*4+c.
__device__ __forceinline__ int posCS3(int i, int c) {
    if (i >= 4 * c + 3)
        return (c == 0) ? i - 3 : (c == 1) ? i + 6 : (c == 2) ? i + 11 : 27;
    int dd = i - 4 * c + 1;
    return 28 + (3 - dd) * 4 + c;
}

// ---- wave-parallel fp32-vs-bf16 probe of a buffer head (uniform per block) ----
__device__ __forceinline__ int probe_f32(const u16* p) {
    int lane = threadIdx.x & 63;
    int e0 = (p[lane] >> 7) & 0xFF;
    int e1 = (p[lane + 64] >> 7) & 0xFF;
    int c = ((e0 < 100 || e0 > 140) ? 1 : 0) + ((e1 < 100 || e1 > 140) ? 1 : 0);
    unsigned long long b1 = __ballot(c >= 1);
    unsigned long long b2 = __ballot(c >= 2);
    return ((__popcll(b1) + __popcll(b2)) > 16) ? 1 : 0;
}

// ---------------- per-input dtype probe (fallback path only) ----------------
__global__ void probe5_kernel(const u16* __restrict__ p0, const u16* __restrict__ p1,
                              const u16* __restrict__ p2, const u16* __restrict__ p3,
                              const u16* __restrict__ p4, int* __restrict__ mode) {
    if (blockIdx.x != 0) return;
    const u16* ps[5] = {p0, p1, p2, p3, p4};
    int lane = threadIdx.x & 63;
    for (int t = 0; t < 5; t++) {
        int e0 = (ps[t][lane] >> 7) & 0xFF;
        int e1 = (ps[t][lane + 64] >> 7) & 0xFF;
        int c = ((e0 < 100 || e0 > 140) ? 1 : 0) + ((e1 < 100 || e1 > 140) ? 1 : 0);
        unsigned long long b1 = __ballot(c >= 1);
        unsigned long long b2 = __ballot(c >= 2);
        if (lane == 0) mode[t] = ((__popcll(b1) + __popcll(b2)) > 16) ? 1 : 0;
    }
}

// ---------------- fused prep: RoPE + weight bf16 conversion ------------------
__global__ __launch_bounds__(512)
void prep_kernel(const void* __restrict__ Xin, u16* __restrict__ Xr,
                 const void* __restrict__ Wq, const void* __restrict__ Wk,
                 const void* __restrict__ Wv, const void* __restrict__ Wo,
                 u16* __restrict__ WB, u16* __restrict__ WoB) {
    int b = blockIdx.x;
    if (b < S_LEN) {
        int md = probe_f32((const u16*)Xin);
        int i = b;
        int j = threadIdx.x;
        float freq = ex2(-(float)j * 0.025952563241307518f);   // 10000^(-j/512)
        float ang  = (float)i * freq;
        float sv, cv;
        sincosf(ang, &sv, &cv);
        int base = i * D_MODEL;
        float xe, xo;
        if (md) {
            float2 xv = *(const float2*)&((const float*)Xin)[base + 2 * j];
            xe = xv.x; xo = xv.y;
        } else {
            ushort2 xv = *(const ushort2*)&((const u16*)Xin)[base + 2 * j];
            xe = b2f(xv.x); xo = b2f(xv.y);
        }
        Xr[base + j]       = f2bu(xe * cv - xo * sv);
        Xr[base + 512 + j] = f2bu(xe * sv + xo * cv);
    } else {
        int bid = b - S_LEN;
        const void* src; u16* dst; int goff;
        if (bid < 256)      { src = Wq; dst = WB;               goff = bid; }
        else if (bid < 320) { src = Wk; dst = WB + 1024 * 1024; goff = bid - 256; }
        else if (bid < 384) { src = Wv; dst = WB + 1280 * 1024; goff = bid - 320; }
        else                { src = Wo; dst = WoB;              goff = bid - 384; }
        int md = probe_f32((const u16*)src);
        size_t g = (size_t)goff * 512 + threadIdx.x;     // 8-elem group
        if (md) {
            const float* f = (const float*)src + g * 8;
            float4 v0 = *(const float4*)f;
            float4 v1 = *(const float4*)(f + 4);
            u16 t[8] = {f2bu(v0.x), f2bu(v0.y), f2bu(v0.z), f2bu(v0.w),
                        f2bu(v1.x), f2bu(v1.y), f2bu(v1.z), f2bu(v1.w)};
            *(uint4*)(dst + g * 8) = *(const uint4*)t;
        } else {
            *(uint4*)(dst + g * 8) = *(const uint4*)((const u16*)src + g * 8);
        }
    }
}

// ---------------- RoPE (fallback path, self-probing) ----------------
__global__ __launch_bounds__(512)
void rope_kernel(const void* __restrict__ Xin, u16* __restrict__ Xr) {
    int md = probe_f32((const u16*)Xin);
    int i = blockIdx.x;
    int j = threadIdx.x;
    float freq = ex2(-(float)j * 0.025952563241307518f);
    float ang  = (float)i * freq;
    float sv, cv;
    sincosf(ang, &sv, &cv);
    int base = i * D_MODEL;
    float xe, xo;
    if (md) {
        float2 xv = *(const float2*)&((const float*)Xin)[base + 2 * j];
        xe = xv.x; xo = xv.y;
    } else {
        ushort2 xv = *(const ushort2*)&((const u16*)Xin)[base + 2 * j];
        xe = b2f(xv.x); xo = b2f(xv.y);
    }
    Xr[base + j]       = f2bu(xe * cv - xo * sv);
    Xr[base + 512 + j] = f2bu(xe * sv + xo * cv);
}

// ---------------- fast GEMM: C = A(bf16) . W^T(bf16), 64x64 tile, BK=64 ------
// BM=64 (was 128): grid 768/512 blocks -> 3/2 blocks/CU (was 1.5/1.0) so the
// per-K-step stage->barrier latency overlaps across co-resident blocks.
// Double-buffered LDS; XCD-aware block swizzle (nwg%8==0); XOR-swizzled LDS.
template<int MODE>
__global__ __launch_bounds__(256)
void gemm_fast(const u16* __restrict__ A, const u16* __restrict__ WBm,
               u16* __restrict__ Qm, u16* __restrict__ Km, u16* __restrict__ Vm,
               float* __restrict__ Cf) {
    __shared__ u16 As[2][4096];   // [64][64] x2
    __shared__ u16 Bs[2][4096];   // [64][64] x2
    const int tid = threadIdx.x;
    const int w = tid >> 6, lane = tid & 63, quad = lane >> 4, lcol = lane & 15;

    // XCD swizzle: flat id (x-fastest dispatch) -> contiguous chunk per XCD
    const int flat = blockIdx.y * gridDim.x + blockIdx.x;
    const int cpx  = (gridDim.x * gridDim.y) >> 3;
    const int ns   = (flat & 7) * cpx + (flat >> 3);
    const int m0 = (ns / gridDim.x) * 64;
    const int n0 = (ns % gridDim.x) * 64;

    const int arl   = lane >> 3;                       // row within 8-row chunk
    const int colsw = ((lane & 7) ^ arl) * 8;          // inverse-swizzled src col

    const u16* ap[2]; const u16* bp[2];
    #pragma unroll
    for (int c = 0; c < 2; c++)
        ap[c] = A + (size_t)(m0 + (c * 4 + w) * 8 + arl) * 1024 + colsw;
    #pragma unroll
    for (int c = 0; c < 2; c++)
        bp[c] = WBm + (size_t)(n0 + (c * 4 + w) * 8 + arl) * 1024 + colsw;

    const int abase = (w * 16 + lcol) * 64;
    const int koff0 = (quad * 8) ^ ((lcol & 7) * 8);
    const int koff1 = koff0 ^ 32;

    ffrag acc[4];
    #pragma unroll
    for (int ct = 0; ct < 4; ct++) acc[ct] = (ffrag)0.0f;

    // prologue: stage k0=0 into buf 0
    #pragma unroll
    for (int c = 0; c < 2; c++) gld_lds16(ap[c], &As[0][(c * 4 + w) * 512]);
    #pragma unroll
    for (int c = 0; c < 2; c++) gld_lds16(bp[c], &Bs[0][(c * 4 + w) * 512]);
    __syncthreads();

    int cur = 0;
    for (int k0 = 0; k0 < D_MODEL; k0 += 64) {
        if (k0 + 64 < D_MODEL) {   // stage next K-step into other buffer (async)
            const int nb = cur ^ 1;
            #pragma unroll
            for (int c = 0; c < 2; c++)
                gld_lds16(ap[c] + k0 + 64, &As[nb][(c * 4 + w) * 512]);
            #pragma unroll
            for (int c = 0; c < 2; c++)
                gld_lds16(bp[c] + k0 + 64, &Bs[nb][(c * 4 + w) * 512]);
        }

        const u16* Ab = &As[cur][0];
        const u16* Bb = &Bs[cur][0];
        const bfrag a0 = *(const bfrag*)&Ab[abase + koff0];
        const bfrag a1 = *(const bfrag*)&Ab[abase + koff1];
        #pragma unroll
        for (int ct = 0; ct < 4; ct++) {
            const int bb = (ct * 16 + lcol) * 64;
            const bfrag b0 = *(const bfrag*)&Bb[bb + koff0];
            acc[ct] = __builtin_amdgcn_mfma_f32_16x16x32_bf16(a0, b0, acc[ct], 0, 0, 0);
            const bfrag b1 = *(const bfrag*)&Bb[bb + koff1];
            acc[ct] = __builtin_amdgcn_mfma_f32_16x16x32_bf16(a1, b1, acc[ct], 0, 0, 0);
        }
        __syncthreads();   // drains this step's staging loads; next buf ready
        cur ^= 1;
    }

    if (MODE == 0) {
        if (n0 < 1280) {
            u16* Cp; int ldc, nc;
            if (n0 < 1024) { Cp = Qm; ldc = 1024; nc = n0; }
            else           { Cp = Km; ldc = 256;  nc = n0 - 1024; }
            #pragma unroll
            for (int ct = 0; ct < 4; ct++)
                #pragma unroll
                for (int r = 0; r < 4; r++) {
                    int row = m0 + w * 16 + quad * 4 + r;
                    Cp[(size_t)row * ldc + nc + ct * 16 + lcol] = f2bu(acc[ct][r]);
                }
        } else {
            const int nc = n0 - 1280;
            #pragma unroll
            for (int ct = 0; ct < 4; ct++)
                #pragma unroll
                for (int r = 0; r < 4; r++) {
                    int row = m0 + w * 16 + quad * 4 + r;   // s
                    int col = nc + ct * 16 + lcol;          // d
                    Vm[(size_t)col * S_LEN + row] = f2bu(acc[ct][r]);
                }
        }
    } else {
        #pragma unroll
        for (int ct = 0; ct < 4; ct++)
            #pragma unroll
            for (int r = 0; r < 4; r++) {
                int row = m0 + w * 16 + quad * 4 + r;
                Cf[(size_t)row * D_MODEL + n0 + ct * 16 + lcol] = acc[ct][r];
            }
    }
}

// ---- helper: stage one B-panel row-chunk from fp32/bf16 weights (fallback) ----
__device__ __forceinline__ void stageB(u16* dst, const void* Bv, size_t off, int md) {
    if (md) {
        const float* Bf = (const float*)Bv;
        float4 b0 = *(const float4*)&Bf[off];
        float4 b1 = *(const float4*)&Bf[off + 4];
        u16 t[8] = {f2bu(b0.x), f2bu(b0.y), f2bu(b0.z), f2bu(b0.w),
                    f2bu(b1.x), f2bu(b1.y), f2bu(b1.z), f2bu(b1.w)};
        *(uint4*)dst = *(const uint4*)t;
    } else {
        *(uint4*)dst = *(const uint4*)&((const u16*)Bv)[off];
    }
}

// ---------------- fallback fused QKV projection (MFMA) ----------
__global__ __launch_bounds__(256)
void qkv_mfma(const u16* __restrict__ Xr, const void* __restrict__ Wq,
              const void* __restrict__ Wk, const void* __restrict__ Wv,
              u16* __restrict__ Qm, u16* __restrict__ Km, u16* __restrict__ Vm,
              const int* __restrict__ mode) {
    __shared__ u16 As[128][36];
    __shared__ u16 Bs[64][36];
    const int tid = threadIdx.x;
    const int w = tid >> 6, lane = tid & 63, quad = lane >> 4, lcol = lane & 15;
    const int m0 = blockIdx.y * 128;
    const int n0 = blockIdx.x * 64;

    const void* Bv; int nb, md;
    if (n0 < 1024)       { Bv = Wq; nb = n0;        md = mode[1]; }
    else if (n0 < 1280)  { Bv = Wk; nb = n0 - 1024; md = mode[2]; }
    else                 { Bv = Wv; nb = n0 - 1280; md = mode[3]; }

    ffrag acc[2][4];
    #pragma unroll
    for (int rf = 0; rf < 2; rf++)
        #pragma unroll
        for (int ct = 0; ct < 4; ct++) acc[rf][ct] = (ffrag)0.0f;

    const int arow = tid >> 2, akc = tid & 3;
    for (int k0 = 0; k0 < D_MODEL; k0 += 32) {
        *(uint4*)&As[arow][akc * 8] =
            *(const uint4*)&Xr[(size_t)(m0 + arow) * D_MODEL + k0 + akc * 8];
        *(uint4*)&As[arow + 64][akc * 8] =
            *(const uint4*)&Xr[(size_t)(m0 + arow + 64) * D_MODEL + k0 + akc * 8];
        stageB(&Bs[arow][akc * 8], Bv, (size_t)(nb + arow) * D_MODEL + k0 + akc * 8, md);
        __syncthreads();
        const bfrag a0 = *(const bfrag*)&As[w * 32 + lcol][quad * 8];
        const bfrag a1 = *(const bfrag*)&As[w * 32 + 16 + lcol][quad * 8];
        #pragma unroll
        for (int ct = 0; ct < 4; ct++) {
            const bfrag b = *(const bfrag*)&Bs[ct * 16 + lcol][quad * 8];
            acc[0][ct] = __builtin_amdgcn_mfma_f32_16x16x32_bf16(a0, b, acc[0][ct], 0, 0, 0);
            acc[1][ct] = __builtin_amdgcn_mfma_f32_16x16x32_bf16(a1, b, acc[1][ct], 0, 0, 0);
        }
        __syncthreads();
    }

    if (n0 < 1280) {
        u16* Cp; int ldc, nc;
        if (n0 < 1024) { Cp = Qm; ldc = 1024; nc = n0; }
        else           { Cp = Km; ldc = 256;  nc = n0 - 1024; }
        #pragma unroll
        for (int rf = 0; rf < 2; rf++)
            #pragma unroll
            for (int ct = 0; ct < 4; ct++)
                #pragma unroll
                for (int r = 0; r < 4; r++) {
                    int row = m0 + w * 32 + rf * 16 + quad * 4 + r;
                    Cp[(size_t)row * ldc + nc + ct * 16 + lcol] = f2bu(acc[rf][ct][r]);
                }
    } else {
        const int nc = n0 - 1280;
        #pragma unroll
        for (int rf = 0; rf < 2; rf++)
            #pragma unroll
            for (int ct = 0; ct < 4; ct++)
                #pragma unroll
                for (int r = 0; r < 4; r++) {
                    int row = m0 + w * 32 + rf * 16 + quad * 4 + r;
                    int col = nc + ct * 16 + lcol;
                    Vm[(size_t)col * S_LEN + row] = f2bu(acc[rf][ct][r]);
                }
    }
}

// ---------------- fallback O projection ----------------
__global__ __launch_bounds__(256)
void oproj_mfma(const u16* __restrict__ A, const void* __restrict__ B,
                float* __restrict__ C, const int* __restrict__ mode) {
    __shared__ u16 As[128][36];
    __shared__ u16 Bs[64][36];
    const int tid = threadIdx.x;
    const int w = tid >> 6, lane = tid & 63, quad = lane >> 4, lcol = lane & 15;
    const int m0 = blockIdx.y * 128;
    const int n0 = blockIdx.x * 64;
    const int md = mode[4];

    ffrag acc[2][4];
    #pragma unroll
    for (int rf = 0; rf < 2; rf++)
        #pragma unroll
        for (int ct = 0; ct < 4; ct++) acc[rf][ct] = (ffrag)0.0f;

    const int arow = tid >> 2, akc = tid & 3;
    for (int k0 = 0; k0 < D_MODEL; k0 += 32) {
        *(uint4*)&As[arow][akc * 8] =
            *(const uint4*)&A[(size_t)(m0 + arow) * D_MODEL + k0 + akc * 8];
        *(uint4*)&As[arow + 64][akc * 8] =
            *(const uint4*)&A[(size_t)(m0 + arow + 64) * D_MODEL + k0 + akc * 8];
        stageB(&Bs[arow][akc * 8], B, (size_t)(n0 + arow) * D_MODEL + k0 + akc * 8, md);
        __syncthreads();
        const bfrag a0 = *(const bfrag*)&As[w * 32 + lcol][quad * 8];
        const bfrag a1 = *(const bfrag*)&As[w * 32 + 16 + lcol][quad * 8];
        #pragma unroll
        for (int ct = 0; ct < 4; ct++) {
            const bfrag b = *(const bfrag*)&Bs[ct * 16 + lcol][quad * 8];
            acc[0][ct] = __builtin_amdgcn_mfma_f32_16x16x32_bf16(a0, b, acc[0][ct], 0, 0, 0);
            acc[1][ct] = __builtin_amdgcn_mfma_f32_16x16x32_bf16(a1, b, acc[1][ct], 0, 0, 0);
        }
        __syncthreads();
    }

    #pragma unroll
    for (int rf = 0; rf < 2; rf++)
        #pragma unroll
        for (int ct = 0; ct < 4; ct++)
            #pragma unroll
            for (int r = 0; r < 4; r++) {
                int row = m0 + w * 32 + rf * 16 + quad * 4 + r;
                C[(size_t)row * D_MODEL + n0 + ct * 16 + lcol] = acc[rf][ct][r];
            }
}

// ---------------- split-K MFMA flash attention partials (swapped QK^T) -------
// QBLK=128, K/V LDS frags shared by two query sets; speculative softmax with
// shuffle-free per-lane overflow guard; diagonal A-set skip.
// NEW: single-chunk blocks (CS=3, i<=3 -> nc==1) normalize in-registers and
// write Om directly (no partial round-trip, no combine work for rows < 512).
template<int CS, int SF>
__global__ __launch_bounds__(256, 3)
void attn_part(const u16* __restrict__ Q, const u16* __restrict__ K,
               const u16* __restrict__ Vt, float* __restrict__ OpF,
               u16* __restrict__ OpH, float2* __restrict__ ml2,
               u16* __restrict__ Om) {
    const int bid = blockIdx.x;
    const int cidx = bid >> 4;
    const int h = bid & 15;
    const int g = h >> 2;

    int i, c;
    if (CS == 3) {
        // longest-first schedule (inverse of posCS3)
        if (cidx < 13)       { c = 0; i = cidx + 3; }
        else if (cidx < 22)  { c = 1; i = cidx - 6; }
        else if (cidx < 27)  { c = 2; i = cidx - 11; }
        else if (cidx == 27) { c = 3; i = 15; }
        else { int t = cidx - 28; int dd = 3 - (t >> 2); c = t & 3; i = 4 * c + dd - 1; }
    } else {
        if (cidx < 8) { i = cidx; c = 0; }
        else          { i = 8 + ((cidx - 8) >> 1); c = (cidx - 8) & 1; }
    }
    const int i0 = i * 128;
    const int tile0 = c << CS;
    const int tlast = min(2 * i + 1, ((c + 1) << CS) - 1);
    const int nt = tlast - tile0 + 1;

    const int tid  = threadIdx.x;
    const int w    = tid >> 6;
    const int lane = tid & 63;
    const int quad = lane >> 4;
    const int lcol = lane & 15;

    __shared__ u16 Ks[2][64][72];
    __shared__ u16 Vts[2][64][72];

    const int qiA = i0 + w * 16 + lcol;
    const int qiB = qiA + 64;
    const bfrag qbA0 = *(const bfrag*)&Q[(size_t)qiA * D_MODEL + h * 64 + quad * 8];
    const bfrag qbA1 = *(const bfrag*)&Q[(size_t)qiA * D_MODEL + h * 64 + 32 + quad * 8];
    const bfrag qbB0 = *(const bfrag*)&Q[(size_t)qiB * D_MODEL + h * 64 + quad * 8];
    const bfrag qbB1 = *(const bfrag*)&Q[(size_t)qiB * D_MODEL + h * 64 + 32 + quad * 8];

    ffrag oaccA[4], oaccB[4];
    #pragma unroll
    for (int ct = 0; ct < 4; ct++) { oaccA[ct] = (ffrag)0.0f; oaccB[ct] = (ffrag)0.0f; }
    float m_runA = 0.0f, l_runA = 0.0f;
    float m_runB = 0.0f, l_runB = 0.0f;

    const int key0 = tid & 63, dc0 = tid >> 6;
    const int vd0 = tid >> 3, vch = tid & 7;
    const int vpos0 = 32 * (vch >> 2) + 16 * (vch & 1) + 4 * ((vch >> 1) & 1);
    const u16* vbase0 = &Vt[(size_t)(g * 64 + vd0) * S_LEN];
    const u16* vbase1 = &Vt[(size_t)(g * 64 + vd0 + 32) * S_LEN];

    int jp = tile0 * 64;
    uint4 kpre0 = *(const uint4*)&K[(size_t)(jp + key0) * KV_DIM + g * 64 + dc0 * 8];
    uint4 kpre1 = *(const uint4*)&K[(size_t)(jp + key0) * KV_DIM + g * 64 + (dc0 + 4) * 8];
    uint4 vpre0 = *(const uint4*)&vbase0[jp + vch * 8];
    uint4 vpre1 = *(const uint4*)&vbase1[jp + vch * 8];

    // prologue: write tile0 into buffer 0
    {
        *(uint4*)&Ks[0][key0][dc0 * 8]       = kpre0;
        *(uint4*)&Ks[0][key0][(dc0 + 4) * 8] = kpre1;
        *(uint2*)&Vts[0][vd0][vpos0]          = make_uint2(vpre0.x, vpre0.y);
        *(uint2*)&Vts[0][vd0][vpos0 + 8]      = make_uint2(vpre0.z, vpre0.w);
        *(uint2*)&Vts[0][vd0 + 32][vpos0]     = make_uint2(vpre1.x, vpre1.y);
        *(uint2*)&Vts[0][vd0 + 32][vpos0 + 8] = make_uint2(vpre1.z, vpre1.w);
    }

    const float CF = 0.18033688f;   // 0.125 * log2(e)
    // overflow guard threshold in RAW score units: 550*CF ~= 99 -> p <= 2^99,
    // l_run <= 2048*2^99 < 2^110: safe in fp32.
    const float GRD = 550.0f;
    int cur = 0;

    for (int tt = 0; tt < nt; tt++) {
        const int tj = tile0 + tt;
        const int j0 = tj * 64;
        const bool hasA = (tj <= 2 * i);   // tj == 2i+1 -> set A fully masked

        if (tt + 1 < nt) {   // issue next-tile loads early (latency under compute)
            const int j0n = (tj + 1) * 64;
            kpre0 = *(const uint4*)&K[(size_t)(j0n + key0) * KV_DIM + g * 64 + dc0 * 8];
            kpre1 = *(const uint4*)&K[(size_t)(j0n + key0) * KV_DIM + g * 64 + (dc0 + 4) * 8];
            vpre0 = *(const uint4*)&vbase0[j0n + vch * 8];
            vpre1 = *(const uint4*)&vbase1[j0n + vch * 8];
        }
        __syncthreads();   // LDS[cur] writes (prev iter / prologue) now visible

        ffrag saccA[4], saccB[4];
        #pragma unroll
        for (int ct = 0; ct < 4; ct++) { saccA[ct] = (ffrag)0.0f; saccB[ct] = (ffrag)0.0f; }
        __builtin_amdgcn_s_setprio(1);
        if (hasA) {
            #pragma unroll
            for (int ct = 0; ct < 4; ct++) {
                const bfrag kb0 = *(const bfrag*)&Ks[cur][ct * 16 + lcol][quad * 8];
                saccA[ct] = __builtin_amdgcn_mfma_f32_16x16x32_bf16(kb0, qbA0, saccA[ct], 0, 0, 0);
                saccB[ct] = __builtin_amdgcn_mfma_f32_16x16x32_bf16(kb0, qbB0, saccB[ct], 0, 0, 0);
                const bfrag kb1 = *(const bfrag*)&Ks[cur][ct * 16 + lcol][32 + quad * 8];
                saccA[ct] = __builtin_amdgcn_mfma_f32_16x16x32_bf16(kb1, qbA1, saccA[ct], 0, 0, 0);
                saccB[ct] = __builtin_amdgcn_mfma_f32_16x16x32_bf16(kb1, qbB1, saccB[ct], 0, 0, 0);
            }
        } else {
            #pragma unroll
            for (int ct = 0; ct < 4; ct++) {
                const bfrag kb0 = *(const bfrag*)&Ks[cur][ct * 16 + lcol][quad * 8];
                saccB[ct] = __builtin_amdgcn_mfma_f32_16x16x32_bf16(kb0, qbB0, saccB[ct], 0, 0, 0);
                const bfrag kb1 = *(const bfrag*)&Ks[cur][ct * 16 + lcol][32 + quad * 8];
                saccB[ct] = __builtin_amdgcn_mfma_f32_16x16x32_bf16(kb1, qbB1, saccB[ct], 0, 0, 0);
            }
        }
        __builtin_amdgcn_s_setprio(0);

        // ---- set A softmax (rows i0 .. i0+63) ----
        bfrag paA0, paA1;
        if (hasA) {
            float svA[4][4];
            if (tj == 2 * i) {
                #pragma unroll
                for (int ct = 0; ct < 4; ct++)
                    #pragma unroll
                    for (int r = 0; r < 4; r++) {
                        int kj = j0 + ct * 16 + quad * 4 + r;
                        svA[ct][r] = (kj <= qiA) ? saccA[ct][r] : -1e30f;
                    }
            } else {
                #pragma unroll
                for (int ct = 0; ct < 4; ct++)
                    #pragma unroll
                    for (int r = 0; r < 4; r++) svA[ct][r] = saccA[ct][r];
            }
            // per-lane max (guard only; no cross-lane shuffle on fast path)
            float tA0 = max3f(svA[0][0], svA[0][1], svA[0][2]);
            float tA1 = max3f(svA[0][3], svA[1][0], svA[1][1]);
            float tA2 = max3f(svA[1][2], svA[1][3], svA[2][0]);
            float tA3 = max3f(svA[2][1], svA[2][2], svA[2][3]);
            float tA4 = max3f(svA[3][0], svA[3][1], svA[3][2]);
            float lA = fmaxf(max3f(tA0, tA1, tA2), max3f(tA3, tA4, svA[3][3]));
            if (!__all(lA <= m_runA + GRD)) {   // slow path (never with these inputs)
                float mx = fmaxf(lA, __shfl_xor(lA, 16, 64));
                mx = fmaxf(mx, __shfl_xor(mx, 32, 64));
                float mnew = fmaxf(m_runA, mx);
                float al = ex2((m_runA - mnew) * CF);
                l_runA *= al;
                #pragma unroll
                for (int r = 0; r < 4; r++) {
                    float ar = __shfl(al, quad * 4 + r, 64);
                    #pragma unroll
                    for (int ct = 0; ct < 4; ct++) oaccA[ct][r] *= ar;
                }
                m_runA = mnew;
            }
            const float mcA = m_runA * CF;
            float rsA = 0.0f;
            #pragma unroll
            for (int ct = 0; ct < 4; ct++)
                #pragma unroll
                for (int r = 0; r < 4; r++) {
                    float p = ex2(svA[ct][r] * CF - mcA);
                    svA[ct][r] = p;
                    rsA += p;
                }
            rsA += __shfl_xor(rsA, 16, 64);
            rsA += __shfl_xor(rsA, 32, 64);
            l_runA += rsA;

            u32x4 pwA0, pwA1;
            pwA0[0] = cvt_pk_bf16(svA[0][0], svA[0][1]);
            pwA0[1] = cvt_pk_bf16(svA[0][2], svA[0][3]);
            pwA0[2] = cvt_pk_bf16(svA[1][0], svA[1][1]);
            pwA0[3] = cvt_pk_bf16(svA[1][2], svA[1][3]);
            pwA1[0] = cvt_pk_bf16(svA[2][0], svA[2][1]);
            pwA1[1] = cvt_pk_bf16(svA[2][2], svA[2][3]);
            pwA1[2] = cvt_pk_bf16(svA[3][0], svA[3][1]);
            pwA1[3] = cvt_pk_bf16(svA[3][2], svA[3][3]);
            paA0 = __builtin_bit_cast(bfrag, pwA0);
            paA1 = __builtin_bit_cast(bfrag, pwA1);
        }

        // ---- set B softmax (rows i0+64 .. i0+127) ----
        float svB[4][4];
        if (tj == 2 * i + 1) {
            #pragma unroll
            for (int ct = 0; ct < 4; ct++)
                #pragma unroll
                for (int r = 0; r < 4; r++) {
                    int kj = j0 + ct * 16 + quad * 4 + r;
                    svB[ct][r] = (kj <= qiB) ? saccB[ct][r] : -1e30f;
                }
        } else {
            #pragma unroll
            for (int ct = 0; ct < 4; ct++)
                #pragma unroll
                for (int r = 0; r < 4; r++) svB[ct][r] = saccB[ct][r];
        }
        float tB0 = max3f(svB[0][0], svB[0][1], svB[0][2]);
        float tB1 = max3f(svB[0][3], svB[1][0], svB[1][1]);
        float tB2 = max3f(svB[1][2], svB[1][3], svB[2][0]);
        float tB3 = max3f(svB[2][1], svB[2][2], svB[2][3]);
        float tB4 = max3f(svB[3][0], svB[3][1], svB[3][2]);
        float lB = fmaxf(max3f(tB0, tB1, tB2), max3f(tB3, tB4, svB[3][3]));
        if (!__all(lB <= m_runB + GRD)) {   // slow path
            float mx = fmaxf(lB, __shfl_xor(lB, 16, 64));
            mx = fmaxf(mx, __shfl_xor(mx, 32, 64));
            float mnew = fmaxf(m_runB, mx);
            float al = ex2((m_runB - mnew) * CF);
            l_runB *= al;
            #pragma unroll
            for (int r = 0; r < 4; r++) {
                float ar = __shfl(al, quad * 4 + r, 64);
                #pragma unroll
                for (int ct = 0; ct < 4; ct++) oaccB[ct][r] *= ar;
            }
            m_runB = mnew;
        }
        const float mcB = m_runB * CF;
        float rsB = 0.0f;
        #pragma unroll
        for (int ct = 0; ct < 4; ct++)
            #pragma unroll
            for (int r = 0; r < 4; r++) {
                float p = ex2(svB[ct][r] * CF - mcB);
                svB[ct][r] = p;
                rsB += p;
            }
        rsB += __shfl_xor(rsB, 16, 64);
        rsB += __shfl_xor(rsB, 32, 64);
        l_runB += rsB;

        u32x4 pwB0, pwB1;
        pwB0[0] = cvt_pk_bf16(svB[0][0], svB[0][1]);
        pwB0[1] = cvt_pk_bf16(svB[0][2], svB[0][3]);
        pwB0[2] = cvt_pk_bf16(svB[1][0], svB[1][1]);
        pwB0[3] = cvt_pk_bf16(svB[1][2], svB[1][3]);
        pwB1[0] = cvt_pk_bf16(svB[2][0], svB[2][1]);
        pwB1[1] = cvt_pk_bf16(svB[2][2], svB[2][3]);
        pwB1[2] = cvt_pk_bf16(svB[3][0], svB[3][1]);
        pwB1[3] = cvt_pk_bf16(svB[3][2], svB[3][3]);
        const bfrag paB0 = __builtin_bit_cast(bfrag, pwB0);
        const bfrag paB1 = __builtin_bit_cast(bfrag, pwB1);

        // ---- PV ----
        __builtin_amdgcn_s_setprio(1);
        if (hasA) {
            #pragma unroll
            for (int ct = 0; ct < 4; ct++) {
                const bfrag vb0 = *(const bfrag*)&Vts[cur][ct * 16 + lcol][quad * 8];
                oaccA[ct] = __builtin_amdgcn_mfma_f32_16x16x32_bf16(paA0, vb0, oaccA[ct], 0, 0, 0);
                oaccB[ct] = __builtin_amdgcn_mfma_f32_16x16x32_bf16(paB0, vb0, oaccB[ct], 0, 0, 0);
                const bfrag vb1 = *(const bfrag*)&Vts[cur][ct * 16 + lcol][32 + quad * 8];
                oaccA[ct] = __builtin_amdgcn_mfma_f32_16x16x32_bf16(paA1, vb1, oaccA[ct], 0, 0, 0);
                oaccB[ct] = __builtin_amdgcn_mfma_f32_16x16x32_bf16(paB1, vb1, oaccB[ct], 0, 0, 0);
            }
        } else {
            #pragma unroll
            for (int ct = 0; ct < 4; ct++) {
                const bfrag vb0 = *(const bfrag*)&Vts[cur][ct * 16 + lcol][quad * 8];
                oaccB[ct] = __builtin_amdgcn_mfma_f32_16x16x32_bf16(paB0, vb0, oaccB[ct], 0, 0, 0);
                const bfrag vb1 = *(const bfrag*)&Vts[cur][ct * 16 + lcol][32 + quad * 8];
                oaccB[ct] = __builtin_amdgcn_mfma_f32_16x16x32_bf16(paB1, vb1, oaccB[ct], 0, 0, 0);
            }
        }
        __builtin_amdgcn_s_setprio(0);

        if (tt + 1 < nt) {   // write-late into the other buffer (no barrier)
            const int nb = cur ^ 1;
            *(uint4*)&Ks[nb][key0][dc0 * 8]       = kpre0;
            *(uint4*)&Ks[nb][key0][(dc0 + 4) * 8] = kpre1;
            *(uint2*)&Vts[nb][vd0][vpos0]          = make_uint2(vpre0.x, vpre0.y);
            *(uint2*)&Vts[nb][vd0][vpos0 + 8]      = make_uint2(vpre0.z, vpre0.w);
            *(uint2*)&Vts[nb][vd0 + 32][vpos0]     = make_uint2(vpre1.x, vpre1.y);
            *(uint2*)&Vts[nb][vd0 + 32][vpos0 + 8] = make_uint2(vpre1.z, vpre1.w);
        }
        cur ^= 1;
    }

    if (CS == 3 && 2 * i + 1 <= 7) {
        // nc==1: this block saw all keys for its rows -> normalize + write Om.
        // (m cancels: oacc and l share the exp(-m*CF) scaling.)
        #pragma unroll
        for (int r = 0; r < 4; r++) {
            float lA = __shfl(l_runA, quad * 4 + r, 64);
            float lB = __shfl(l_runB, quad * 4 + r, 64);
            float invA = 1.0f / lA;
            float invB = 1.0f / lB;
            int rowA = i0 + w * 16 + quad * 4 + r;
            #pragma unroll
            for (int ct = 0; ct < 4; ct++) {
                Om[(size_t)rowA * D_MODEL + h * 64 + ct * 16 + lcol] =
                    f2bu(oaccA[ct][r] * invA);
                Om[(size_t)(rowA + 64) * D_MODEL + h * 64 + ct * 16 + lcol] =
                    f2bu(oaccB[ct][r] * invB);
            }
        }
        return;
    }

    // store un-normalized partials (128 rows x 64 cols per block) + (m,l)
    #pragma unroll
    for (int ct = 0; ct < 4; ct++)
        #pragma unroll
        for (int r = 0; r < 4; r++) {
            int rowA = w * 16 + quad * 4 + r;
            size_t offA = (size_t)bid * 8192 + rowA * 64 + ct * 16 + lcol;
            size_t offB = offA + 4096;   // rows +64
            if (SF) { OpF[offA] = oaccA[ct][r]; OpF[offB] = oaccB[ct][r]; }
            else    { OpH[offA] = f2bu(oaccA[ct][r]); OpH[offB] = f2bu(oaccB[ct][r]); }
        }
    if (quad == 0) {
        ml2[(size_t)bid * 128 + w * 16 + lcol]      = make_float2(m_runA * 0.125f, l_runA);
        ml2[(size_t)bid * 128 + 64 + w * 16 + lcol] = make_float2(m_runB * 0.125f, l_runB);
    }
}

// ---------------- combine partials -> Om (bf16) ----------------
// CS==3: rows < 512 (i<=3) were written directly by attn_part; grid = 1536,
// row = blockIdx.x + 512.
template<int CS, int SF>
__global__ __launch_bounds__(256)
void attn_combine(const float* __restrict__ OpF, const u16* __restrict__ OpH,
                  const float2* __restrict__ ml2, u16* __restrict__ Om) {
    const int row = blockIdx.x + ((CS == 3) ? 512 : 0);
    const int i = row >> 7;          // 128-row q tiles
    const int r = row & 127;
    const int t = threadIdx.x;
    const int h = t >> 4;
    const int d = (t & 15) * 4;
    const int nc = (CS == 3) ? ((2 * i + 1) >> 3) + 1 : ((2 * i + 1) >> 4) + 1;

    float M = -1e30f;
    for (int c = 0; c < nc; c++) {
        int pos = (CS == 3) ? posCS3(i, c) : ((i < 8) ? i : 8 + 2 * (i - 8) + c);
        float2 m = ml2[(size_t)(pos * 16 + h) * 128 + r];
        M = fmaxf(M, m.x);
    }
    float L = 0.0f;
    float acc[4] = {0.0f, 0.0f, 0.0f, 0.0f};
    for (int c = 0; c < nc; c++) {
        int pos = (CS == 3) ? posCS3(i, c) : ((i < 8) ? i : 8 + 2 * (i - 8) + c);
        float2 m = ml2[(size_t)(pos * 16 + h) * 128 + r];
        float wgt = __expf(m.x - M);
        L += m.y * wgt;
        size_t off = (size_t)(pos * 16 + h) * 8192 + r * 64 + d;
        if (SF) {
            float4 v = *(const float4*)&OpF[off];
            acc[0] += v.x * wgt; acc[1] += v.y * wgt;
            acc[2] += v.z * wgt; acc[3] += v.w * wgt;
        } else {
            ushort4 v = *(const ushort4*)&OpH[off];
            acc[0] += b2f(v.x) * wgt; acc[1] += b2f(v.y) * wgt;
            acc[2] += b2f(v.z) * wgt; acc[3] += b2f(v.w) * wgt;
        }
    }
    float inv = 1.0f / L;
    #pragma unroll
    for (int k = 0; k < 4; k++)
        Om[(size_t)row * D_MODEL + h * 64 + d + k] = f2bu(acc[k] * inv);
}

extern "C" void kernel_launch(void* const* d_in, const int* in_sizes, int n_in,
                              void* d_out, int out_size, void* d_ws, size_t ws_size,
                              hipStream_t stream) {
    const void* X  = d_in[0];
    const void* Wq = d_in[1];
    const void* Wk = d_in[2];
    const void* Wv = d_in[3];
    const void* Wo = d_in[4];
    float* out = (float*)d_out;

    u16* XrB = (u16*)d_out;   // 4MB scratch in d_out, dead after qkv

    // ws: mode 64B | Qm 4MB | Km 1MB | Vt 1MB | Om 4MB   (= 10,485,824)
    //     | OpF 20,971,520 | ml2 655,360                  (= 32,112,704 = needA)
    //     | WB 3,145,728 | WoB 2,097,152                  (= 37,355,584 = needFull)
    int* mode = (int*)d_ws;
    u16* Qm = (u16*)((char*)d_ws + 64);
    u16* Km = Qm + (size_t)S_LEN * D_MODEL;
    u16* Vm = Km + (size_t)S_LEN * KV_DIM;
    u16* Om = Vm + (size_t)S_LEN * KV_DIM;

    const size_t needA    = 10485824ULL + 20971520ULL + 655360ULL;   // 32,112,704
    const size_t needFull = needA + 3145728ULL + 2097152ULL;         // 37,355,584

    if (ws_size >= needFull) {
        // ---- fast path: fused prep + 64-tile dbuf GEMMs + direct-write attn ----
        float*  OpF = (float*)((char*)d_ws + 10485824);
        float2* ml2 = (float2*)((char*)d_ws + 10485824 + 20971520);
        u16*    WB  = (u16*)((char*)d_ws + needA);
        u16*    WoB = WB + (size_t)1536 * 1024;

        prep_kernel<<<S_LEN + 640, 512, 0, stream>>>(X, XrB, Wq, Wk, Wv, Wo, WB, WoB);
        gemm_fast<0><<<dim3(24, 32), 256, 0, stream>>>(XrB, WB, Qm, Km, Vm, nullptr);
        attn_part<3, 1><<<40 * 16, 256, 0, stream>>>(Qm, Km, Vm, OpF, nullptr, ml2, Om);
        attn_combine<3, 1><<<S_LEN - 512, 256, 0, stream>>>(OpF, nullptr, ml2, Om);
        gemm_fast<1><<<dim3(16, 32), 256, 0, stream>>>(Om, WoB, nullptr, nullptr, nullptr, out);
    } else {
        rope_kernel<<<S_LEN, 512, 0, stream>>>(X, XrB);
        probe5_kernel<<<1, 64, 0, stream>>>(
            (const u16*)X, (const u16*)Wq, (const u16*)Wk, (const u16*)Wv,
            (const u16*)Wo, mode);
        qkv_mfma<<<dim3((D_MODEL + 2 * KV_DIM) / 64, S_LEN / 128), 256, 0, stream>>>(
            XrB, Wq, Wk, Wv, Qm, Km, Vm, mode);
        if (ws_size >= needA) {
            float*  OpF = (float*)((char*)d_ws + 10485824);
            float2* ml2 = (float2*)((char*)d_ws + 10485824 + 20971520);
            attn_part<3, 1><<<40 * 16, 256, 0, stream>>>(Qm, Km, Vm, OpF, nullptr, ml2, Om);
            attn_combine<3, 1><<<S_LEN - 512, 256, 0, stream>>>(OpF, nullptr, ml2, Om);
        } else {
            u16*    OpH = (u16*)d_out;
            float2* ml2 = (float2*)((char*)d_out + (size_t)768 * 4096 * 2);
            attn_part<4, 0><<<24 * 16, 256, 0, stream>>>(Qm, Km, Vm, nullptr, OpH, ml2, Om);
            attn_combine<4, 0><<<S_LEN, 256, 0, stream>>>(nullptr, OpH, ml2, Om);
        }
        oproj_mfma<<<dim3(D_MODEL / 64, S_LEN / 128), 256, 0, stream>>>(Om, Wo, out, mode);
    }
}

// Round 10
// 134.534 us; speedup vs baseline: 1.0244x; 1.0244x over previous
//
#include <hip/hip_runtime.h>
#include <hip/hip_bf16.h>

#define S_LEN   2048
#define D_MODEL 1024
#define N_HEADS 16
#define N_GROUPS 4
#define D_K     64
#define KV_DIM  (N_GROUPS * D_K)   // 256

typedef __hip_bfloat16 bf16;
typedef unsigned short u16;
typedef __attribute__((ext_vector_type(8))) short bfrag;   // 8 bf16 = 4 VGPR
typedef __attribute__((ext_vector_type(4))) float ffrag;   // 4 fp32 acc
typedef __attribute__((ext_vector_type(4))) unsigned int u32x4;

__device__ __forceinline__ float b2f(u16 u) {
    return __uint_as_float(((unsigned)u) << 16);
}
__device__ __forceinline__ u16 f2bu(float f) {
    bf16 h = __float2bfloat16(f);
    return __builtin_bit_cast(u16, h);
}
__device__ __forceinline__ unsigned cvt_pk_bf16(float lo, float hi) {
    unsigned r;
    asm("v_cvt_pk_bf16_f32 %0, %1, %2" : "=v"(r) : "v"(lo), "v"(hi));
    return r;
}
__device__ __forceinline__ float max3f(float a, float b, float c) {
    float d;
    asm("v_max3_f32 %0, %1, %2, %3" : "=v"(d) : "v"(a), "v"(b), "v"(c));
    return d;
}
__device__ __forceinline__ float ex2(float x) {
#if __has_builtin(__builtin_amdgcn_exp2f)
    return __builtin_amdgcn_exp2f(x);
#else
    return __expf(x * 0.69314718f);
#endif
}

typedef __attribute__((address_space(3))) u16 lds_u16;
typedef __attribute__((address_space(1))) const u16 glb_u16;
__device__ __forceinline__ void gld_lds16(const u16* g, u16* l) {
    __builtin_amdgcn_global_load_lds((glb_u16*)g, (lds_u16*)l, 16, 0, 0);
}

// ---- longest-first chunk schedule for CS=3, QBLK=128 (40 chunks) ----
// Full (nt=8) chunks: (i,c) with i >= 4c+3 -> positions 0..27 (c-major).
// Partial chunks nt=2d (d=i-4c+1 in {1,2,3}) at 28+(3-d)*4+c.
__device__ __forceinline__ int posCS3(int i, int c) {
    if (i >= 4 * c + 3)
        return (c == 0) ? i - 3 : (c == 1) ? i + 6 : (c == 2) ? i + 11 : 27;
    int dd = i - 4 * c + 1;
    return 28 + (3 - dd) * 4 + c;
}

// ---- wave-parallel fp32-vs-bf16 probe of a buffer head (uniform per block) ----
__device__ __forceinline__ int probe_f32(const u16* p) {
    int lane = threadIdx.x & 63;
    int e0 = (p[lane] >> 7) & 0xFF;
    int e1 = (p[lane + 64] >> 7) & 0xFF;
    int c = ((e0 < 100 || e0 > 140) ? 1 : 0) + ((e1 < 100 || e1 > 140) ? 1 : 0);
    unsigned long long b1 = __ballot(c >= 1);
    unsigned long long b2 = __ballot(c >= 2);
    return ((__popcll(b1) + __popcll(b2)) > 16) ? 1 : 0;
}

// ---------------- per-input dtype probe (fallback path only) ----------------
__global__ void probe5_kernel(const u16* __restrict__ p0, const u16* __restrict__ p1,
                              const u16* __restrict__ p2, const u16* __restrict__ p3,
                              const u16* __restrict__ p4, int* __restrict__ mode) {
    if (blockIdx.x != 0) return;
    const u16* ps[5] = {p0, p1, p2, p3, p4};
    int lane = threadIdx.x & 63;
    for (int t = 0; t < 5; t++) {
        int e0 = (ps[t][lane] >> 7) & 0xFF;
        int e1 = (ps[t][lane + 64] >> 7) & 0xFF;
        int c = ((e0 < 100 || e0 > 140) ? 1 : 0) + ((e1 < 100 || e1 > 140) ? 1 : 0);
        unsigned long long b1 = __ballot(c >= 1);
        unsigned long long b2 = __ballot(c >= 2);
        if (lane == 0) mode[t] = ((__popcll(b1) + __popcll(b2)) > 16) ? 1 : 0;
    }
}

// ---------------- fused prep: RoPE + weight bf16 conversion ------------------
__global__ __launch_bounds__(512)
void prep_kernel(const void* __restrict__ Xin, u16* __restrict__ Xr,
                 const void* __restrict__ Wq, const void* __restrict__ Wk,
                 const void* __restrict__ Wv, const void* __restrict__ Wo,
                 u16* __restrict__ WB, u16* __restrict__ WoB) {
    int b = blockIdx.x;
    if (b < S_LEN) {
        int md = probe_f32((const u16*)Xin);
        int i = b;
        int j = threadIdx.x;
        float freq = ex2(-(float)j * 0.025952563241307518f);   // 10000^(-j/512)
        float ang  = (float)i * freq;
        float sv, cv;
        sincosf(ang, &sv, &cv);
        int base = i * D_MODEL;
        float xe, xo;
        if (md) {
            float2 xv = *(const float2*)&((const float*)Xin)[base + 2 * j];
            xe = xv.x; xo = xv.y;
        } else {
            ushort2 xv = *(const ushort2*)&((const u16*)Xin)[base + 2 * j];
            xe = b2f(xv.x); xo = b2f(xv.y);
        }
        Xr[base + j]       = f2bu(xe * cv - xo * sv);
        Xr[base + 512 + j] = f2bu(xe * sv + xo * cv);
    } else {
        int bid = b - S_LEN;
        const void* src; u16* dst; int goff;
        if (bid < 256)      { src = Wq; dst = WB;               goff = bid; }
        else if (bid < 320) { src = Wk; dst = WB + 1024 * 1024; goff = bid - 256; }
        else if (bid < 384) { src = Wv; dst = WB + 1280 * 1024; goff = bid - 320; }
        else                { src = Wo; dst = WoB;              goff = bid - 384; }
        int md = probe_f32((const u16*)src);
        size_t g = (size_t)goff * 512 + threadIdx.x;     // 8-elem group
        if (md) {
            const float* f = (const float*)src + g * 8;
            float4 v0 = *(const float4*)f;
            float4 v1 = *(const float4*)(f + 4);
            u16 t[8] = {f2bu(v0.x), f2bu(v0.y), f2bu(v0.z), f2bu(v0.w),
                        f2bu(v1.x), f2bu(v1.y), f2bu(v1.z), f2bu(v1.w)};
            *(uint4*)(dst + g * 8) = *(const uint4*)t;
        } else {
            *(uint4*)(dst + g * 8) = *(const uint4*)((const u16*)src + g * 8);
        }
    }
}

// ---------------- RoPE (fallback path, self-probing) ----------------
__global__ __launch_bounds__(512)
void rope_kernel(const void* __restrict__ Xin, u16* __restrict__ Xr) {
    int md = probe_f32((const u16*)Xin);
    int i = blockIdx.x;
    int j = threadIdx.x;
    float freq = ex2(-(float)j * 0.025952563241307518f);
    float ang  = (float)i * freq;
    float sv, cv;
    sincosf(ang, &sv, &cv);
    int base = i * D_MODEL;
    float xe, xo;
    if (md) {
        float2 xv = *(const float2*)&((const float*)Xin)[base + 2 * j];
        xe = xv.x; xo = xv.y;
    } else {
        ushort2 xv = *(const ushort2*)&((const u16*)Xin)[base + 2 * j];
        xe = b2f(xv.x); xo = b2f(xv.y);
    }
    Xr[base + j]       = f2bu(xe * cv - xo * sv);
    Xr[base + 512 + j] = f2bu(xe * sv + xo * cv);
}

// ---------------- fast GEMM: C = A(bf16) . W^T(bf16), 128x64 tile, BK=64 -----
// (R8-proven shape; R9's BM=64 experiment regressed: halved per-block MFMA
// work at same barrier cost + doubled B staging traffic.)
// Double-buffered LDS; XCD-aware block swizzle (nwg%8==0); XOR-swizzled LDS.
template<int MODE>
__global__ __launch_bounds__(256)
void gemm_fast(const u16* __restrict__ A, const u16* __restrict__ WBm,
               u16* __restrict__ Qm, u16* __restrict__ Km, u16* __restrict__ Vm,
               float* __restrict__ Cf) {
    __shared__ u16 As[2][8192];   // [128][64] x2
    __shared__ u16 Bs[2][4096];   // [64][64]  x2
    const int tid = threadIdx.x;
    const int w = tid >> 6, lane = tid & 63, quad = lane >> 4, lcol = lane & 15;

    // XCD swizzle: flat id (x-fastest dispatch) -> contiguous chunk per XCD
    const int flat = blockIdx.y * gridDim.x + blockIdx.x;
    const int cpx  = (gridDim.x * gridDim.y) >> 3;
    const int ns   = (flat & 7) * cpx + (flat >> 3);
    const int m0 = (ns / gridDim.x) * 128;
    const int n0 = (ns % gridDim.x) * 64;

    const int arl   = lane >> 3;                       // row within 8-row chunk
    const int colsw = ((lane & 7) ^ arl) * 8;          // inverse-swizzled src col

    const u16* ap[4]; const u16* bp[2];
    #pragma unroll
    for (int c = 0; c < 4; c++)
        ap[c] = A + (size_t)(m0 + (c * 4 + w) * 8 + arl) * 1024 + colsw;
    #pragma unroll
    for (int c = 0; c < 2; c++)
        bp[c] = WBm + (size_t)(n0 + (c * 4 + w) * 8 + arl) * 1024 + colsw;

    const int abase = (w * 32 + lcol) * 64;
    const int koff0 = (quad * 8) ^ ((lcol & 7) * 8);
    const int koff1 = koff0 ^ 32;

    ffrag acc[2][4];
    #pragma unroll
    for (int rf = 0; rf < 2; rf++)
        #pragma unroll
        for (int ct = 0; ct < 4; ct++) acc[rf][ct] = (ffrag)0.0f;

    // prologue: stage k0=0 into buf 0
    #pragma unroll
    for (int c = 0; c < 4; c++) gld_lds16(ap[c], &As[0][(c * 4 + w) * 512]);
    #pragma unroll
    for (int c = 0; c < 2; c++) gld_lds16(bp[c], &Bs[0][(c * 4 + w) * 512]);
    __syncthreads();

    int cur = 0;
    for (int k0 = 0; k0 < D_MODEL; k0 += 64) {
        if (k0 + 64 < D_MODEL) {   // stage next K-step into other buffer (async)
            const int nb = cur ^ 1;
            #pragma unroll
            for (int c = 0; c < 4; c++)
                gld_lds16(ap[c] + k0 + 64, &As[nb][(c * 4 + w) * 512]);
            #pragma unroll
            for (int c = 0; c < 2; c++)
                gld_lds16(bp[c] + k0 + 64, &Bs[nb][(c * 4 + w) * 512]);
        }

        const u16* Ab = &As[cur][0];
        const u16* Bb = &Bs[cur][0];
        const bfrag a00 = *(const bfrag*)&Ab[abase + koff0];
        const bfrag a10 = *(const bfrag*)&Ab[abase + 1024 + koff0];
        const bfrag a01 = *(const bfrag*)&Ab[abase + koff1];
        const bfrag a11 = *(const bfrag*)&Ab[abase + 1024 + koff1];
        #pragma unroll
        for (int ct = 0; ct < 4; ct++) {
            const int bb = (ct * 16 + lcol) * 64;
            const bfrag b0 = *(const bfrag*)&Bb[bb + koff0];
            acc[0][ct] = __builtin_amdgcn_mfma_f32_16x16x32_bf16(a00, b0, acc[0][ct], 0, 0, 0);
            acc[1][ct] = __builtin_amdgcn_mfma_f32_16x16x32_bf16(a10, b0, acc[1][ct], 0, 0, 0);
            const bfrag b1 = *(const bfrag*)&Bb[bb + koff1];
            acc[0][ct] = __builtin_amdgcn_mfma_f32_16x16x32_bf16(a01, b1, acc[0][ct], 0, 0, 0);
            acc[1][ct] = __builtin_amdgcn_mfma_f32_16x16x32_bf16(a11, b1, acc[1][ct], 0, 0, 0);
        }
        __syncthreads();   // drains this step's staging loads; next buf ready
        cur ^= 1;
    }

    if (MODE == 0) {
        if (n0 < 1280) {
            u16* Cp; int ldc, nc;
            if (n0 < 1024) { Cp = Qm; ldc = 1024; nc = n0; }
            else           { Cp = Km; ldc = 256;  nc = n0 - 1024; }
            #pragma unroll
            for (int rf = 0; rf < 2; rf++)
                #pragma unroll
                for (int ct = 0; ct < 4; ct++)
                    #pragma unroll
                    for (int r = 0; r < 4; r++) {
                        int row = m0 + w * 32 + rf * 16 + quad * 4 + r;
                        Cp[(size_t)row * ldc + nc + ct * 16 + lcol] = f2bu(acc[rf][ct][r]);
                    }
        } else {
            const int nc = n0 - 1280;
            #pragma unroll
            for (int rf = 0; rf < 2; rf++)
                #pragma unroll
                for (int ct = 0; ct < 4; ct++)
                    #pragma unroll
                    for (int r = 0; r < 4; r++) {
                        int row = m0 + w * 32 + rf * 16 + quad * 4 + r;   // s
                        int col = nc + ct * 16 + lcol;                    // d
                        Vm[(size_t)col * S_LEN + row] = f2bu(acc[rf][ct][r]);
                    }
        }
    } else {
        #pragma unroll
        for (int rf = 0; rf < 2; rf++)
            #pragma unroll
            for (int ct = 0; ct < 4; ct++)
                #pragma unroll
                for (int r = 0; r < 4; r++) {
                    int row = m0 + w * 32 + rf * 16 + quad * 4 + r;
                    Cf[(size_t)row * D_MODEL + n0 + ct * 16 + lcol] = acc[rf][ct][r];
                }
    }
}

// ---- helper: stage one B-panel row-chunk from fp32/bf16 weights (fallback) ----
__device__ __forceinline__ void stageB(u16* dst, const void* Bv, size_t off, int md) {
    if (md) {
        const float* Bf = (const float*)Bv;
        float4 b0 = *(const float4*)&Bf[off];
        float4 b1 = *(const float4*)&Bf[off + 4];
        u16 t[8] = {f2bu(b0.x), f2bu(b0.y), f2bu(b0.z), f2bu(b0.w),
                    f2bu(b1.x), f2bu(b1.y), f2bu(b1.z), f2bu(b1.w)};
        *(uint4*)dst = *(const uint4*)t;
    } else {
        *(uint4*)dst = *(const uint4*)&((const u16*)Bv)[off];
    }
}

// ---------------- fallback fused QKV projection (MFMA) ----------
__global__ __launch_bounds__(256)
void qkv_mfma(const u16* __restrict__ Xr, const void* __restrict__ Wq,
              const void* __restrict__ Wk, const void* __restrict__ Wv,
              u16* __restrict__ Qm, u16* __restrict__ Km, u16* __restrict__ Vm,
              const int* __restrict__ mode) {
    __shared__ u16 As[128][36];
    __shared__ u16 Bs[64][36];
    const int tid = threadIdx.x;
    const int w = tid >> 6, lane = tid & 63, quad = lane >> 4, lcol = lane & 15;
    const int m0 = blockIdx.y * 128;
    const int n0 = blockIdx.x * 64;

    const void* Bv; int nb, md;
    if (n0 < 1024)       { Bv = Wq; nb = n0;        md = mode[1]; }
    else if (n0 < 1280)  { Bv = Wk; nb = n0 - 1024; md = mode[2]; }
    else                 { Bv = Wv; nb = n0 - 1280; md = mode[3]; }

    ffrag acc[2][4];
    #pragma unroll
    for (int rf = 0; rf < 2; rf++)
        #pragma unroll
        for (int ct = 0; ct < 4; ct++) acc[rf][ct] = (ffrag)0.0f;

    const int arow = tid >> 2, akc = tid & 3;
    for (int k0 = 0; k0 < D_MODEL; k0 += 32) {
        *(uint4*)&As[arow][akc * 8] =
            *(const uint4*)&Xr[(size_t)(m0 + arow) * D_MODEL + k0 + akc * 8];
        *(uint4*)&As[arow + 64][akc * 8] =
            *(const uint4*)&Xr[(size_t)(m0 + arow + 64) * D_MODEL + k0 + akc * 8];
        stageB(&Bs[arow][akc * 8], Bv, (size_t)(nb + arow) * D_MODEL + k0 + akc * 8, md);
        __syncthreads();
        const bfrag a0 = *(const bfrag*)&As[w * 32 + lcol][quad * 8];
        const bfrag a1 = *(const bfrag*)&As[w * 32 + 16 + lcol][quad * 8];
        #pragma unroll
        for (int ct = 0; ct < 4; ct++) {
            const bfrag b = *(const bfrag*)&Bs[ct * 16 + lcol][quad * 8];
            acc[0][ct] = __builtin_amdgcn_mfma_f32_16x16x32_bf16(a0, b, acc[0][ct], 0, 0, 0);
            acc[1][ct] = __builtin_amdgcn_mfma_f32_16x16x32_bf16(a1, b, acc[1][ct], 0, 0, 0);
        }
        __syncthreads();
    }

    if (n0 < 1280) {
        u16* Cp; int ldc, nc;
        if (n0 < 1024) { Cp = Qm; ldc = 1024; nc = n0; }
        else           { Cp = Km; ldc = 256;  nc = n0 - 1024; }
        #pragma unroll
        for (int rf = 0; rf < 2; rf++)
            #pragma unroll
            for (int ct = 0; ct < 4; ct++)
                #pragma unroll
                for (int r = 0; r < 4; r++) {
                    int row = m0 + w * 32 + rf * 16 + quad * 4 + r;
                    Cp[(size_t)row * ldc + nc + ct * 16 + lcol] = f2bu(acc[rf][ct][r]);
                }
    } else {
        const int nc = n0 - 1280;
        #pragma unroll
        for (int rf = 0; rf < 2; rf++)
            #pragma unroll
            for (int ct = 0; ct < 4; ct++)
                #pragma unroll
                for (int r = 0; r < 4; r++) {
                    int row = m0 + w * 32 + rf * 16 + quad * 4 + r;
                    int col = nc + ct * 16 + lcol;
                    Vm[(size_t)col * S_LEN + row] = f2bu(acc[rf][ct][r]);
                }
    }
}

// ---------------- fallback O projection ----------------
__global__ __launch_bounds__(256)
void oproj_mfma(const u16* __restrict__ A, const void* __restrict__ B,
                float* __restrict__ C, const int* __restrict__ mode) {
    __shared__ u16 As[128][36];
    __shared__ u16 Bs[64][36];
    const int tid = threadIdx.x;
    const int w = tid >> 6, lane = tid & 63, quad = lane >> 4, lcol = lane & 15;
    const int m0 = blockIdx.y * 128;
    const int n0 = blockIdx.x * 64;
    const int md = mode[4];

    ffrag acc[2][4];
    #pragma unroll
    for (int rf = 0; rf < 2; rf++)
        #pragma unroll
        for (int ct = 0; ct < 4; ct++) acc[rf][ct] = (ffrag)0.0f;

    const int arow = tid >> 2, akc = tid & 3;
    for (int k0 = 0; k0 < D_MODEL; k0 += 32) {
        *(uint4*)&As[arow][akc * 8] =
            *(const uint4*)&A[(size_t)(m0 + arow) * D_MODEL + k0 + akc * 8];
        *(uint4*)&As[arow + 64][akc * 8] =
            *(const uint4*)&A[(size_t)(m0 + arow + 64) * D_MODEL + k0 + akc * 8];
        stageB(&Bs[arow][akc * 8], B, (size_t)(n0 + arow) * D_MODEL + k0 + akc * 8, md);
        __syncthreads();
        const bfrag a0 = *(const bfrag*)&As[w * 32 + lcol][quad * 8];
        const bfrag a1 = *(const bfrag*)&As[w * 32 + 16 + lcol][quad * 8];
        #pragma unroll
        for (int ct = 0; ct < 4; ct++) {
            const bfrag b = *(const bfrag*)&Bs[ct * 16 + lcol][quad * 8];
            acc[0][ct] = __builtin_amdgcn_mfma_f32_16x16x32_bf16(a0, b, acc[0][ct], 0, 0, 0);
            acc[1][ct] = __builtin_amdgcn_mfma_f32_16x16x32_bf16(a1, b, acc[1][ct], 0, 0, 0);
        }
        __syncthreads();
    }

    #pragma unroll
    for (int rf = 0; rf < 2; rf++)
        #pragma unroll
        for (int ct = 0; ct < 4; ct++)
            #pragma unroll
            for (int r = 0; r < 4; r++) {
                int row = m0 + w * 32 + rf * 16 + quad * 4 + r;
                C[(size_t)row * D_MODEL + n0 + ct * 16 + lcol] = acc[rf][ct][r];
            }
}

// ---------------- split-K MFMA flash attention partials (swapped QK^T) -------
// QBLK=128, K/V LDS frags shared by two query sets; speculative softmax with
// shuffle-free per-lane overflow guard; diagonal A-set skip; single-chunk
// blocks (CS=3, i<=3 -> nc==1) normalize in-registers and write Om directly.
template<int CS, int SF>
__global__ __launch_bounds__(256, 3)
void attn_part(const u16* __restrict__ Q, const u16* __restrict__ K,
               const u16* __restrict__ Vt, float* __restrict__ OpF,
               u16* __restrict__ OpH, float2* __restrict__ ml2,
               u16* __restrict__ Om) {
    const int bid = blockIdx.x;
    const int cidx = bid >> 4;
    const int h = bid & 15;
    const int g = h >> 2;

    int i, c;
    if (CS == 3) {
        // longest-first schedule (inverse of posCS3)
        if (cidx < 13)       { c = 0; i = cidx + 3; }
        else if (cidx < 22)  { c = 1; i = cidx - 6; }
        else if (cidx < 27)  { c = 2; i = cidx - 11; }
        else if (cidx == 27) { c = 3; i = 15; }
        else { int t = cidx - 28; int dd = 3 - (t >> 2); c = t & 3; i = 4 * c + dd - 1; }
    } else {
        if (cidx < 8) { i = cidx; c = 0; }
        else          { i = 8 + ((cidx - 8) >> 1); c = (cidx - 8) & 1; }
    }
    const int i0 = i * 128;
    const int tile0 = c << CS;
    const int tlast = min(2 * i + 1, ((c + 1) << CS) - 1);
    const int nt = tlast - tile0 + 1;

    const int tid  = threadIdx.x;
    const int w    = tid >> 6;
    const int lane = tid & 63;
    const int quad = lane >> 4;
    const int lcol = lane & 15;

    __shared__ u16 Ks[2][64][72];
    __shared__ u16 Vts[2][64][72];

    const int qiA = i0 + w * 16 + lcol;
    const int qiB = qiA + 64;
    const bfrag qbA0 = *(const bfrag*)&Q[(size_t)qiA * D_MODEL + h * 64 + quad * 8];
    const bfrag qbA1 = *(const bfrag*)&Q[(size_t)qiA * D_MODEL + h * 64 + 32 + quad * 8];
    const bfrag qbB0 = *(const bfrag*)&Q[(size_t)qiB * D_MODEL + h * 64 + quad * 8];
    const bfrag qbB1 = *(const bfrag*)&Q[(size_t)qiB * D_MODEL + h * 64 + 32 + quad * 8];

    ffrag oaccA[4], oaccB[4];
    #pragma unroll
    for (int ct = 0; ct < 4; ct++) { oaccA[ct] = (ffrag)0.0f; oaccB[ct] = (ffrag)0.0f; }
    float m_runA = 0.0f, l_runA = 0.0f;
    float m_runB = 0.0f, l_runB = 0.0f;

    const int key0 = tid & 63, dc0 = tid >> 6;
    const int vd0 = tid >> 3, vch = tid & 7;
    const int vpos0 = 32 * (vch >> 2) + 16 * (vch & 1) + 4 * ((vch >> 1) & 1);
    const u16* vbase0 = &Vt[(size_t)(g * 64 + vd0) * S_LEN];
    const u16* vbase1 = &Vt[(size_t)(g * 64 + vd0 + 32) * S_LEN];

    int jp = tile0 * 64;
    uint4 kpre0 = *(const uint4*)&K[(size_t)(jp + key0) * KV_DIM + g * 64 + dc0 * 8];
    uint4 kpre1 = *(const uint4*)&K[(size_t)(jp + key0) * KV_DIM + g * 64 + (dc0 + 4) * 8];
    uint4 vpre0 = *(const uint4*)&vbase0[jp + vch * 8];
    uint4 vpre1 = *(const uint4*)&vbase1[jp + vch * 8];

    // prologue: write tile0 into buffer 0
    {
        *(uint4*)&Ks[0][key0][dc0 * 8]       = kpre0;
        *(uint4*)&Ks[0][key0][(dc0 + 4) * 8] = kpre1;
        *(uint2*)&Vts[0][vd0][vpos0]          = make_uint2(vpre0.x, vpre0.y);
        *(uint2*)&Vts[0][vd0][vpos0 + 8]      = make_uint2(vpre0.z, vpre0.w);
        *(uint2*)&Vts[0][vd0 + 32][vpos0]     = make_uint2(vpre1.x, vpre1.y);
        *(uint2*)&Vts[0][vd0 + 32][vpos0 + 8] = make_uint2(vpre1.z, vpre1.w);
    }

    const float CF = 0.18033688f;   // 0.125 * log2(e)
    // overflow guard threshold in RAW score units: 550*CF ~= 99 -> p <= 2^99,
    // l_run <= 2048*2^99 < 2^110: safe in fp32.
    const float GRD = 550.0f;
    int cur = 0;

    for (int tt = 0; tt < nt; tt++) {
        const int tj = tile0 + tt;
        const int j0 = tj * 64;
        const bool hasA = (tj <= 2 * i);   // tj == 2i+1 -> set A fully masked

        if (tt + 1 < nt) {   // issue next-tile loads early (latency under compute)
            const int j0n = (tj + 1) * 64;
            kpre0 = *(const uint4*)&K[(size_t)(j0n + key0) * KV_DIM + g * 64 + dc0 * 8];
            kpre1 = *(const uint4*)&K[(size_t)(j0n + key0) * KV_DIM + g * 64 + (dc0 + 4) * 8];
            vpre0 = *(const uint4*)&vbase0[j0n + vch * 8];
            vpre1 = *(const uint4*)&vbase1[j0n + vch * 8];
        }
        __syncthreads();   // LDS[cur] writes (prev iter / prologue) now visible

        ffrag saccA[4], saccB[4];
        #pragma unroll
        for (int ct = 0; ct < 4; ct++) { saccA[ct] = (ffrag)0.0f; saccB[ct] = (ffrag)0.0f; }
        __builtin_amdgcn_s_setprio(1);
        if (hasA) {
            #pragma unroll
            for (int ct = 0; ct < 4; ct++) {
                const bfrag kb0 = *(const bfrag*)&Ks[cur][ct * 16 + lcol][quad * 8];
                saccA[ct] = __builtin_amdgcn_mfma_f32_16x16x32_bf16(kb0, qbA0, saccA[ct], 0, 0, 0);
                saccB[ct] = __builtin_amdgcn_mfma_f32_16x16x32_bf16(kb0, qbB0, saccB[ct], 0, 0, 0);
                const bfrag kb1 = *(const bfrag*)&Ks[cur][ct * 16 + lcol][32 + quad * 8];
                saccA[ct] = __builtin_amdgcn_mfma_f32_16x16x32_bf16(kb1, qbA1, saccA[ct], 0, 0, 0);
                saccB[ct] = __builtin_amdgcn_mfma_f32_16x16x32_bf16(kb1, qbB1, saccB[ct], 0, 0, 0);
            }
        } else {
            #pragma unroll
            for (int ct = 0; ct < 4; ct++) {
                const bfrag kb0 = *(const bfrag*)&Ks[cur][ct * 16 + lcol][quad * 8];
                saccB[ct] = __builtin_amdgcn_mfma_f32_16x16x32_bf16(kb0, qbB0, saccB[ct], 0, 0, 0);
                const bfrag kb1 = *(const bfrag*)&Ks[cur][ct * 16 + lcol][32 + quad * 8];
                saccB[ct] = __builtin_amdgcn_mfma_f32_16x16x32_bf16(kb1, qbB1, saccB[ct], 0, 0, 0);
            }
        }
        __builtin_amdgcn_s_setprio(0);

        // ---- set A softmax (rows i0 .. i0+63) ----
        bfrag paA0, paA1;
        if (hasA) {
            float svA[4][4];
            if (tj == 2 * i) {
                #pragma unroll
                for (int ct = 0; ct < 4; ct++)
                    #pragma unroll
                    for (int r = 0; r < 4; r++) {
                        int kj = j0 + ct * 16 + quad * 4 + r;
                        svA[ct][r] = (kj <= qiA) ? saccA[ct][r] : -1e30f;
                    }
            } else {
                #pragma unroll
                for (int ct = 0; ct < 4; ct++)
                    #pragma unroll
                    for (int r = 0; r < 4; r++) svA[ct][r] = saccA[ct][r];
            }
            // per-lane max (guard only; no cross-lane shuffle on fast path)
            float tA0 = max3f(svA[0][0], svA[0][1], svA[0][2]);
            float tA1 = max3f(svA[0][3], svA[1][0], svA[1][1]);
            float tA2 = max3f(svA[1][2], svA[1][3], svA[2][0]);
            float tA3 = max3f(svA[2][1], svA[2][2], svA[2][3]);
            float tA4 = max3f(svA[3][0], svA[3][1], svA[3][2]);
            float lA = fmaxf(max3f(tA0, tA1, tA2), max3f(tA3, tA4, svA[3][3]));
            if (!__all(lA <= m_runA + GRD)) {   // slow path (never with these inputs)
                float mx = fmaxf(lA, __shfl_xor(lA, 16, 64));
                mx = fmaxf(mx, __shfl_xor(mx, 32, 64));
                float mnew = fmaxf(m_runA, mx);
                float al = ex2((m_runA - mnew) * CF);
                l_runA *= al;
                #pragma unroll
                for (int r = 0; r < 4; r++) {
                    float ar = __shfl(al, quad * 4 + r, 64);
                    #pragma unroll
                    for (int ct = 0; ct < 4; ct++) oaccA[ct][r] *= ar;
                }
                m_runA = mnew;
            }
            const float mcA = m_runA * CF;
            float rsA = 0.0f;
            #pragma unroll
            for (int ct = 0; ct < 4; ct++)
                #pragma unroll
                for (int r = 0; r < 4; r++) {
                    float p = ex2(svA[ct][r] * CF - mcA);
                    svA[ct][r] = p;
                    rsA += p;
                }
            rsA += __shfl_xor(rsA, 16, 64);
            rsA += __shfl_xor(rsA, 32, 64);
            l_runA += rsA;

            u32x4 pwA0, pwA1;
            pwA0[0] = cvt_pk_bf16(svA[0][0], svA[0][1]);
            pwA0[1] = cvt_pk_bf16(svA[0][2], svA[0][3]);
            pwA0[2] = cvt_pk_bf16(svA[1][0], svA[1][1]);
            pwA0[3] = cvt_pk_bf16(svA[1][2], svA[1][3]);
            pwA1[0] = cvt_pk_bf16(svA[2][0], svA[2][1]);
            pwA1[1] = cvt_pk_bf16(svA[2][2], svA[2][3]);
            pwA1[2] = cvt_pk_bf16(svA[3][0], svA[3][1]);
            pwA1[3] = cvt_pk_bf16(svA[3][2], svA[3][3]);
            paA0 = __builtin_bit_cast(bfrag, pwA0);
            paA1 = __builtin_bit_cast(bfrag, pwA1);
        }

        // ---- set B softmax (rows i0+64 .. i0+127) ----
        float svB[4][4];
        if (tj == 2 * i + 1) {
            #pragma unroll
            for (int ct = 0; ct < 4; ct++)
                #pragma unroll
                for (int r = 0; r < 4; r++) {
                    int kj = j0 + ct * 16 + quad * 4 + r;
                    svB[ct][r] = (kj <= qiB) ? saccB[ct][r] : -1e30f;
                }
        } else {
            #pragma unroll
            for (int ct = 0; ct < 4; ct++)
                #pragma unroll
                for (int r = 0; r < 4; r++) svB[ct][r] = saccB[ct][r];
        }
        float tB0 = max3f(svB[0][0], svB[0][1], svB[0][2]);
        float tB1 = max3f(svB[0][3], svB[1][0], svB[1][1]);
        float tB2 = max3f(svB[1][2], svB[1][3], svB[2][0]);
        float tB3 = max3f(svB[2][1], svB[2][2], svB[2][3]);
        float tB4 = max3f(svB[3][0], svB[3][1], svB[3][2]);
        float lB = fmaxf(max3f(tB0, tB1, tB2), max3f(tB3, tB4, svB[3][3]));
        if (!__all(lB <= m_runB + GRD)) {   // slow path
            float mx = fmaxf(lB, __shfl_xor(lB, 16, 64));
            mx = fmaxf(mx, __shfl_xor(mx, 32, 64));
            float mnew = fmaxf(m_runB, mx);
            float al = ex2((m_runB - mnew) * CF);
            l_runB *= al;
            #pragma unroll
            for (int r = 0; r < 4; r++) {
                float ar = __shfl(al, quad * 4 + r, 64);
                #pragma unroll
                for (int ct = 0; ct < 4; ct++) oaccB[ct][r] *= ar;
            }
            m_runB = mnew;
        }
        const float mcB = m_runB * CF;
        float rsB = 0.0f;
        #pragma unroll
        for (int ct = 0; ct < 4; ct++)
            #pragma unroll
            for (int r = 0; r < 4; r++) {
                float p = ex2(svB[ct][r] * CF - mcB);
                svB[ct][r] = p;
                rsB += p;
            }
        rsB += __shfl_xor(rsB, 16, 64);
        rsB += __shfl_xor(rsB, 32, 64);
        l_runB += rsB;

        u32x4 pwB0, pwB1;
        pwB0[0] = cvt_pk_bf16(svB[0][0], svB[0][1]);
        pwB0[1] = cvt_pk_bf16(svB[0][2], svB[0][3]);
        pwB0[2] = cvt_pk_bf16(svB[1][0], svB[1][1]);
        pwB0[3] = cvt_pk_bf16(svB[1][2], svB[1][3]);
        pwB1[0] = cvt_pk_bf16(svB[2][0], svB[2][1]);
        pwB1[1] = cvt_pk_bf16(svB[2][2], svB[2][3]);
        pwB1[2] = cvt_pk_bf16(svB[3][0], svB[3][1]);
        pwB1[3] = cvt_pk_bf16(svB[3][2], svB[3][3]);
        const bfrag paB0 = __builtin_bit_cast(bfrag, pwB0);
        const bfrag paB1 = __builtin_bit_cast(bfrag, pwB1);

        // ---- PV ----
        __builtin_amdgcn_s_setprio(1);
        if (hasA) {
            #pragma unroll
            for (int ct = 0; ct < 4; ct++) {
                const bfrag vb0 = *(const bfrag*)&Vts[cur][ct * 16 + lcol][quad * 8];
                oaccA[ct] = __builtin_amdgcn_mfma_f32_16x16x32_bf16(paA0, vb0, oaccA[ct], 0, 0, 0);
                oaccB[ct] = __builtin_amdgcn_mfma_f32_16x16x32_bf16(paB0, vb0, oaccB[ct], 0, 0, 0);
                const bfrag vb1 = *(const bfrag*)&Vts[cur][ct * 16 + lcol][32 + quad * 8];
                oaccA[ct] = __builtin_amdgcn_mfma_f32_16x16x32_bf16(paA1, vb1, oaccA[ct], 0, 0, 0);
                oaccB[ct] = __builtin_amdgcn_mfma_f32_16x16x32_bf16(paB1, vb1, oaccB[ct], 0, 0, 0);
            }
        } else {
            #pragma unroll
            for (int ct = 0; ct < 4; ct++) {
                const bfrag vb0 = *(const bfrag*)&Vts[cur][ct * 16 + lcol][quad * 8];
                oaccB[ct] = __builtin_amdgcn_mfma_f32_16x16x32_bf16(paB0, vb0, oaccB[ct], 0, 0, 0);
                const bfrag vb1 = *(const bfrag*)&Vts[cur][ct * 16 + lcol][32 + quad * 8];
                oaccB[ct] = __builtin_amdgcn_mfma_f32_16x16x32_bf16(paB1, vb1, oaccB[ct], 0, 0, 0);
            }
        }
        __builtin_amdgcn_s_setprio(0);

        if (tt + 1 < nt) {   // write-late into the other buffer (no barrier)
            const int nb = cur ^ 1;
            *(uint4*)&Ks[nb][key0][dc0 * 8]       = kpre0;
            *(uint4*)&Ks[nb][key0][(dc0 + 4) * 8] = kpre1;
            *(uint2*)&Vts[nb][vd0][vpos0]          = make_uint2(vpre0.x, vpre0.y);
            *(uint2*)&Vts[nb][vd0][vpos0 + 8]      = make_uint2(vpre0.z, vpre0.w);
            *(uint2*)&Vts[nb][vd0 + 32][vpos0]     = make_uint2(vpre1.x, vpre1.y);
            *(uint2*)&Vts[nb][vd0 + 32][vpos0 + 8] = make_uint2(vpre1.z, vpre1.w);
        }
        cur ^= 1;
    }

    if (CS == 3 && 2 * i + 1 <= 7) {
        // nc==1: this block saw all keys for its rows -> normalize + write Om.
        #pragma unroll
        for (int r = 0; r < 4; r++) {
            float lA = __shfl(l_runA, quad * 4 + r, 64);
            float lB = __shfl(l_runB, quad * 4 + r, 64);
            float invA = 1.0f / lA;
            float invB = 1.0f / lB;
            int rowA = i0 + w * 16 + quad * 4 + r;
            #pragma unroll
            for (int ct = 0; ct < 4; ct++) {
                Om[(size_t)rowA * D_MODEL + h * 64 + ct * 16 + lcol] =
                    f2bu(oaccA[ct][r] * invA);
                Om[(size_t)(rowA + 64) * D_MODEL + h * 64 + ct * 16 + lcol] =
                    f2bu(oaccB[ct][r] * invB);
            }
        }
        return;
    }

    // store un-normalized partials (128 rows x 64 cols per block) + (m,l)
    #pragma unroll
    for (int ct = 0; ct < 4; ct++)
        #pragma unroll
        for (int r = 0; r < 4; r++) {
            int rowA = w * 16 + quad * 4 + r;
            size_t offA = (size_t)bid * 8192 + rowA * 64 + ct * 16 + lcol;
            size_t offB = offA + 4096;   // rows +64
            if (SF) { OpF[offA] = oaccA[ct][r]; OpF[offB] = oaccB[ct][r]; }
            else    { OpH[offA] = f2bu(oaccA[ct][r]); OpH[offB] = f2bu(oaccB[ct][r]); }
        }
    if (quad == 0) {
        ml2[(size_t)bid * 128 + w * 16 + lcol]      = make_float2(m_runA * 0.125f, l_runA);
        ml2[(size_t)bid * 128 + 64 + w * 16 + lcol] = make_float2(m_runB * 0.125f, l_runB);
    }
}

// ---------------- combine partials -> Om (bf16) ----------------
// CS==3: rows < 512 (i<=3) were written directly by attn_part; grid = 1536,
// row = blockIdx.x + 512.
template<int CS, int SF>
__global__ __launch_bounds__(256)
void attn_combine(const float* __restrict__ OpF, const u16* __restrict__ OpH,
                  const float2* __restrict__ ml2, u16* __restrict__ Om) {
    const int row = blockIdx.x + ((CS == 3) ? 512 : 0);
    const int i = row >> 7;          // 128-row q tiles
    const int r = row & 127;
    const int t = threadIdx.x;
    const int h = t >> 4;
    const int d = (t & 15) * 4;
    const int nc = (CS == 3) ? ((2 * i + 1) >> 3) + 1 : ((2 * i + 1) >> 4) + 1;

    float M = -1e30f;
    for (int c = 0; c < nc; c++) {
        int pos = (CS == 3) ? posCS3(i, c) : ((i < 8) ? i : 8 + 2 * (i - 8) + c);
        float2 m = ml2[(size_t)(pos * 16 + h) * 128 + r];
        M = fmaxf(M, m.x);
    }
    float L = 0.0f;
    float acc[4] = {0.0f, 0.0f, 0.0f, 0.0f};
    for (int c = 0; c < nc; c++) {
        int pos = (CS == 3) ? posCS3(i, c) : ((i < 8) ? i : 8 + 2 * (i - 8) + c);
        float2 m = ml2[(size_t)(pos * 16 + h) * 128 + r];
        float wgt = __expf(m.x - M);
        L += m.y * wgt;
        size_t off = (size_t)(pos * 16 + h) * 8192 + r * 64 + d;
        if (SF) {
            float4 v = *(const float4*)&OpF[off];
            acc[0] += v.x * wgt; acc[1] += v.y * wgt;
            acc[2] += v.z * wgt; acc[3] += v.w * wgt;
        } else {
            ushort4 v = *(const ushort4*)&OpH[off];
            acc[0] += b2f(v.x) * wgt; acc[1] += b2f(v.y) * wgt;
            acc[2] += b2f(v.z) * wgt; acc[3] += b2f(v.w) * wgt;
        }
    }
    float inv = 1.0f / L;
    #pragma unroll
    for (int k = 0; k < 4; k++)
        Om[(size_t)row * D_MODEL + h * 64 + d + k] = f2bu(acc[k] * inv);
}

extern "C" void kernel_launch(void* const* d_in, const int* in_sizes, int n_in,
                              void* d_out, int out_size, void* d_ws, size_t ws_size,
                              hipStream_t stream) {
    const void* X  = d_in[0];
    const void* Wq = d_in[1];
    const void* Wk = d_in[2];
    const void* Wv = d_in[3];
    const void* Wo = d_in[4];
    float* out = (float*)d_out;

    u16* XrB = (u16*)d_out;   // 4MB scratch in d_out, dead after qkv

    // ws: mode 64B | Qm 4MB | Km 1MB | Vt 1MB | Om 4MB   (= 10,485,824)
    //     | OpF 20,971,520 | ml2 655,360                  (= 32,112,704 = needA)
    //     | WB 3,145,728 | WoB 2,097,152                  (= 37,355,584 = needFull)
    int* mode = (int*)d_ws;
    u16* Qm = (u16*)((char*)d_ws + 64);
    u16* Km = Qm + (size_t)S_LEN * D_MODEL;
    u16* Vm = Km + (size_t)S_LEN * KV_DIM;
    u16* Om = Vm + (size_t)S_LEN * KV_DIM;

    const size_t needA    = 10485824ULL + 20971520ULL + 655360ULL;   // 32,112,704
    const size_t needFull = needA + 3145728ULL + 2097152ULL;         // 37,355,584

    if (ws_size >= needFull) {
        // ---- fast path: fused prep + 128-tile dbuf GEMMs + direct-write attn ----
        float*  OpF = (float*)((char*)d_ws + 10485824);
        float2* ml2 = (float2*)((char*)d_ws + 10485824 + 20971520);
        u16*    WB  = (u16*)((char*)d_ws + needA);
        u16*    WoB = WB + (size_t)1536 * 1024;

        prep_kernel<<<S_LEN + 640, 512, 0, stream>>>(X, XrB, Wq, Wk, Wv, Wo, WB, WoB);
        gemm_fast<0><<<dim3(24, 16), 256, 0, stream>>>(XrB, WB, Qm, Km, Vm, nullptr);
        attn_part<3, 1><<<40 * 16, 256, 0, stream>>>(Qm, Km, Vm, OpF, nullptr, ml2, Om);
        attn_combine<3, 1><<<S_LEN - 512, 256, 0, stream>>>(OpF, nullptr, ml2, Om);
        gemm_fast<1><<<dim3(16, 16), 256, 0, stream>>>(Om, WoB, nullptr, nullptr, nullptr, out);
    } else {
        rope_kernel<<<S_LEN, 512, 0, stream>>>(X, XrB);
        probe5_kernel<<<1, 64, 0, stream>>>(
            (const u16*)X, (const u16*)Wq, (const u16*)Wk, (const u16*)Wv,
            (const u16*)Wo, mode);
        qkv_mfma<<<dim3((D_MODEL + 2 * KV_DIM) / 64, S_LEN / 128), 256, 0, stream>>>(
            XrB, Wq, Wk, Wv, Qm, Km, Vm, mode);
        if (ws_size >= needA) {
            float*  OpF = (float*)((char*)d_ws + 10485824);
            float2* ml2 = (float2*)((char*)d_ws + 10485824 + 20971520);
            attn_part<3, 1><<<40 * 16, 256, 0, stream>>>(Qm, Km, Vm, OpF, nullptr, ml2, Om);
            attn_combine<3, 1><<<S_LEN - 512, 256, 0, stream>>>(OpF, nullptr, ml2, Om);
        } else {
            u16*    OpH = (u16*)d_out;
            float2* ml2 = (float2*)((char*)d_out + (size_t)768 * 4096 * 2);
            attn_part<4, 0><<<24 * 16, 256, 0, stream>>>(Qm, Km, Vm, nullptr, OpH, ml2, Om);
            attn_combine<4, 0><<<S_LEN, 256, 0, stream>>>(nullptr, OpH, ml2, Om);
        }
        oproj_mfma<<<dim3(D_MODEL / 64, S_LEN / 128), 256, 0, stream>>>(Om, Wo, out, mode);
    }
}